// Round 21
// baseline (229.269 us; speedup 1.0000x reference)
//
#include <hip/hip_runtime.h>
#include <hip/hip_bf16.h>
#include <math.h>

#define NN 50000
#define NE 800000
#define NK 4
#define FD 128
#define CD 32
#define CAP 48       // fixed per-node CSR capacity
#define BNCH 1000    // bn stat chunks (50 rows each)
#define BNROWS 50
#define NRANGE 6250  // NN/8 nodes per XCD range

typedef unsigned short u16;

__device__ __forceinline__ u16 f2bf(float x) {
    union { float f; unsigned u; } c; c.f = x;
    unsigned r = c.u + 0x7fffu + ((c.u >> 16) & 1u);  // RNE
    return (u16)(r >> 16);
}
__device__ __forceinline__ float bflo(unsigned pair) {
    union { unsigned u; float f; } c; c.u = pair << 16;
    return c.f;
}
__device__ __forceinline__ float bfhi(unsigned pair) {
    union { unsigned u; float f; } c; c.u = pair & 0xffff0000u;
    return c.f;
}

// ---------------- XCD-binned fixed-cap CSR scatter ----------------

__global__ void k_scatter(const int* __restrict__ src, const int* __restrict__ dst,
                          const float* __restrict__ ew,
                          int* __restrict__ cnt, int4* __restrict__ sse) {
    int xcd = blockIdx.x & 7;
    int e = (blockIdx.x >> 3) * 256 + threadIdx.x;   // NE divisible by 256
    int d = dst[e];
    int lo = xcd * NRANGE;
    if ((unsigned)(d - lo) < (unsigned)NRANGE) {
        int p = atomicAdd(&cnt[d], 1);
        unsigned w01 = (unsigned)f2bf(ew[e]) | ((unsigned)f2bf(ew[(size_t)NE + e]) << 16);
        unsigned w23 = (unsigned)f2bf(ew[(size_t)2 * NE + e]) | ((unsigned)f2bf(ew[(size_t)3 * NE + e]) << 16);
        sse[(size_t)d * CAP + p] = make_int4(src[e], (int)w01, (int)w23, 0);
    }
}

// ---------------- fused encoder + y0 (y0 stored bf16 [N][32]) ----------------

__global__ void __launch_bounds__(256) k_enc_y0(const float* __restrict__ x,
                                                const float* __restrict__ W,
                                                const float* __restrict__ b,
                                                const float* __restrict__ W1,
                                                float* __restrict__ out,
                                                u16* __restrict__ y0) {
    __shared__ float xsT[FD][68];
    int tid = threadIdx.x;
    int nbase = blockIdx.x * 64;

    int r = tid >> 2;
    int cg = (tid & 3) * 32;
    int gn = nbase + r;
    const float* xr = x + (size_t)(gn < NN ? gn : NN - 1) * FD;
#pragma unroll
    for (int q = 0; q < 8; ++q) {
        float4 v = *(const float4*)(xr + cg + q * 4);
        int f = cg + q * 4;
        xsT[f][r] = v.x; xsT[f + 1][r] = v.y; xsT[f + 2][r] = v.z; xsT[f + 3][r] = v.w;
    }
    __syncthreads();

    int cq = (tid & 31) * 4;
    int col = tid & 31;
    int g = tid >> 5;
    float acc[8][4];
    float acy[8];
#pragma unroll
    for (int i = 0; i < 8; ++i) {
        acy[i] = 0.f;
#pragma unroll
        for (int j = 0; j < 4; ++j) acc[i][j] = 0.f;
    }

    for (int f = 0; f < FD; ++f) {
        float4 wv = *(const float4*)(W + f * FD + cq);
        float w1 = W1[f * CD + col];
        float4 xa = *(const float4*)&xsT[f][g * 8];
        float4 xb = *(const float4*)&xsT[f][g * 8 + 4];
        float xn[8] = {xa.x, xa.y, xa.z, xa.w, xb.x, xb.y, xb.z, xb.w};
#pragma unroll
        for (int i = 0; i < 8; ++i) {
            acc[i][0] += xn[i] * wv.x;
            acc[i][1] += xn[i] * wv.y;
            acc[i][2] += xn[i] * wv.z;
            acc[i][3] += xn[i] * wv.w;
            acy[i] += xn[i] * w1;
        }
    }
    float4 bv = *(const float4*)(b + cq);
#pragma unroll
    for (int i = 0; i < 8; ++i) {
        int n = nbase + g * 8 + i;
        if (n < NN) {
            float4 o;
            o.x = acc[i][0] + bv.x;
            o.y = acc[i][1] + bv.y;
            o.z = acc[i][2] + bv.z;
            o.w = acc[i][3] + bv.w;
            *(float4*)(out + (size_t)n * FD + cq) = o;
            y0[(size_t)n * CD + col] = f2bf(acy[i]);
        }
    }
}

// ---------------- fused aggregation + relu + MLP2 -> u fp32 [N][128] ----------------
// Block = 16 nodes: 4 waves x 4 serial nodes. QUARTER-WAVE per edge: 16 lanes per
// edge, each gathering uint4 (8 bf16 feats) -> per 8 edges only 2 sse + 2 gather
// load instrs (vs 4+4 in the uint2 scheme), each gather a 1KB wave burst.
// Combine across the 4 edge-groups via shfl_xor(16) + shfl_xor(32).

template <int STRIDE>
__global__ void __launch_bounds__(256) k_aggr(const u16* __restrict__ y,
                                              const int* __restrict__ cnt,
                                              const int4* __restrict__ sse,
                                              const float* __restrict__ b1,
                                              const float* __restrict__ W2,
                                              const float* __restrict__ b2,
                                              float* __restrict__ u) {
    __shared__ float W2s[CD][CD];
    __shared__ float b2s[CD];
    __shared__ float tls[4][NK][36];   // per-wave slot; stride 36 dwords
    int tid = threadIdx.x;
    for (int i = tid; i < CD * CD; i += 256) W2s[i >> 5][i & 31] = W2[i];
    if (tid < CD) b2s[tid] = b2[tid];
    __syncthreads();

    int w = tid >> 6;
    int lane = tid & 63;

    // aggregation-phase mapping: quarter-wave per edge
    int e2 = lane >> 4;          // edge within quad (0..3)
    int s16 = lane & 15;
    int ka = s16 >> 2;           // community
    int fo = (s16 & 3) * 8;      // feature octet base
    int col = (STRIDE == CD) ? fo : (ka * CD + fo);
    const u16* yb = y + col;
    bool klow = ka < 2;
    int lsh = (ka & 1) ? 0 : 16;

    // MLP2-phase mapping (unchanged)
    int hi = lane >> 5;
    int sub = lane & 31;
    int km = sub >> 3;
    int f0m = (sub & 7) * 4;

    int nbase0 = blockIdx.x * 16 + w * 4;
    int4 c4 = *(const int4*)(cnt + nbase0);
    int cdeg[4] = {c4.x, c4.y, c4.z, c4.w};

    float4 bv0 = *(const float4*)(b1 + fo);
    float4 bv1 = *(const float4*)(b1 + fo + 4);
    float4 b2v = *(const float4*)&b2s[f0m];

#pragma unroll 1
    for (int it = 0; it < 4; ++it) {
        int node = nbase0 + it;
        int beg = node * CAP;
        int end = beg + cdeg[it];

        float a0 = 0.f, a1 = 0.f, a2 = 0.f, a3 = 0.f;
        float a4 = 0.f, a5 = 0.f, a6 = 0.f, a7 = 0.f;
        for (int j0 = beg; j0 < end; j0 += 8) {
            int ssv[2];
            float wwv[2];
#pragma unroll
            for (int q = 0; q < 2; ++q) {
                int jj = j0 + q * 4 + e2;
                bool ok = jj < end;
                int jc = ok ? jj : beg;
                int4 ee = sse[jc];
                ssv[q] = ee.x;
                unsigned wp = klow ? (unsigned)ee.y : (unsigned)ee.z;
                unsigned wb = (wp << lsh) & 0xffff0000u;
                union { unsigned u; float f; } cv; cv.u = wb;
                wwv[q] = ok ? cv.f : 0.f;
            }
#pragma unroll
            for (int q = 0; q < 2; ++q) {
                uint4 pv = *(const uint4*)(yb + (size_t)ssv[q] * STRIDE);
                float wq = wwv[q];
                a0 += wq * bflo(pv.x); a1 += wq * bfhi(pv.x);
                a2 += wq * bflo(pv.y); a3 += wq * bfhi(pv.y);
                a4 += wq * bflo(pv.z); a5 += wq * bfhi(pv.z);
                a6 += wq * bflo(pv.w); a7 += wq * bfhi(pv.w);
            }
        }
        // butterfly combine over the 4 edge-groups (lane bits 4 and 5)
        a0 += __shfl_xor(a0, 16); a0 += __shfl_xor(a0, 32);
        a1 += __shfl_xor(a1, 16); a1 += __shfl_xor(a1, 32);
        a2 += __shfl_xor(a2, 16); a2 += __shfl_xor(a2, 32);
        a3 += __shfl_xor(a3, 16); a3 += __shfl_xor(a3, 32);
        a4 += __shfl_xor(a4, 16); a4 += __shfl_xor(a4, 32);
        a5 += __shfl_xor(a5, 16); a5 += __shfl_xor(a5, 32);
        a6 += __shfl_xor(a6, 16); a6 += __shfl_xor(a6, 32);
        a7 += __shfl_xor(a7, 16); a7 += __shfl_xor(a7, 32);

        uint4 hv = *(const uint4*)(yb + (size_t)node * STRIDE);
        float t0 = fmaxf(bflo(hv.x) + a0 + bv0.x, 0.f);
        float t1 = fmaxf(bfhi(hv.x) + a1 + bv0.y, 0.f);
        float t2 = fmaxf(bflo(hv.y) + a2 + bv0.z, 0.f);
        float t3 = fmaxf(bfhi(hv.y) + a3 + bv0.w, 0.f);
        float t4 = fmaxf(bflo(hv.z) + a4 + bv1.x, 0.f);
        float t5 = fmaxf(bfhi(hv.z) + a5 + bv1.y, 0.f);
        float t6 = fmaxf(bflo(hv.w) + a6 + bv1.z, 0.f);
        float t7 = fmaxf(bfhi(hv.w) + a7 + bv1.w, 0.f);
        if (e2 == 0) {
            float4 ta = {t0, t1, t2, t3};
            float4 tb = {t4, t5, t6, t7};
            *(float4*)&tls[w][ka][fo] = ta;
            *(float4*)&tls[w][ka][fo + 4] = tb;
        }
        __threadfence_block();  // wave-local LDS ordering

        // MLP2: u[node][km*32+f0m..+3] = sum_m t[m]*W2[m][f0m..+3] + b2
        int m0 = hi * 16;
        float c0 = 0.f, c1 = 0.f, c2 = 0.f, c3 = 0.f;
#pragma unroll
        for (int mm = 0; mm < 16; ++mm) {
            float tm = tls[w][km][m0 + mm];
            float4 wv = *(const float4*)&W2s[m0 + mm][f0m];
            c0 += tm * wv.x;
            c1 += tm * wv.y;
            c2 += tm * wv.z;
            c3 += tm * wv.w;
        }
        c0 += __shfl_xor(c0, 32);
        c1 += __shfl_xor(c1, 32);
        c2 += __shfl_xor(c2, 32);
        c3 += __shfl_xor(c3, 32);
        if (hi == 0) {
            float4 o = {c0 + b2v.x, c1 + b2v.y, c2 + b2v.z, c3 + b2v.w};
            *(float4*)(u + (size_t)node * FD + km * CD + f0m) = o;   // coalesced
        }
        __threadfence_block();  // tls write of next iter ordered after reads
    }
}

// ---------------- batchnorm stats (two-stage, deterministic; u [N][128]) ----------------

__global__ void __launch_bounds__(256) k_bn_stats1(const float* __restrict__ u,
                                                   float* __restrict__ part) {
    int ch = blockIdx.x;
    int c = threadIdx.x & 127;
    int rg = threadIdx.x >> 7;  // 0/1
    float s1 = 0.f, s2 = 0.f;
    int nend = (ch + 1) * BNROWS;
    for (int n = ch * BNROWS + rg; n < nend; n += 2) {
        float v = u[(size_t)n * FD + c];
        s1 += v;
        s2 += v * v;
    }
    __shared__ float sh1[2][FD], sh2[2][FD];
    sh1[rg][c] = s1;
    sh2[rg][c] = s2;
    __syncthreads();
    if (rg == 0) {
        s1 += sh1[1][c];
        s2 += sh2[1][c];
        float2 p = {s1, s2};
        *(float2*)(part + ((size_t)ch * FD + c) * 2) = p;
    }
}

// stage 2: one block PER FEATURE (128 blocks); 256 threads tree-reduce 1000 chunks.
__global__ void __launch_bounds__(256) k_bn_stats2(const float* __restrict__ part,
                                                   const float* __restrict__ gamma,
                                                   const float* __restrict__ beta,
                                                   float* __restrict__ bnp) {
    int c = blockIdx.x;     // feature 0..127
    int tid = threadIdx.x;
    float S1 = 0.f, S2 = 0.f;
    for (int ch = tid; ch < BNCH; ch += 256) {
        float2 p = *(const float2*)(part + ((size_t)ch * FD + c) * 2);
        S1 += p.x;
        S2 += p.y;
    }
    __shared__ float sh1[256], sh2[256];
    sh1[tid] = S1;
    sh2[tid] = S2;
    __syncthreads();
    for (int off = 128; off > 0; off >>= 1) {
        if (tid < off) {
            sh1[tid] += sh1[tid + off];
            sh2[tid] += sh2[tid + off];
        }
        __syncthreads();
    }
    if (tid == 0) {
        float mean = sh1[0] / (float)NN;
        float var = sh2[0] / (float)NN - mean * mean;
        int f = c & 31;
        float scale = gamma[f] * rsqrtf(var + 1e-5f);
        bnp[c * 2] = scale;
        bnp[c * 2 + 1] = beta[f] - mean * scale;
    }
}

// ---------------- fused BN-apply + y1 (streaming, u [N][128]) ----------------

__global__ void __launch_bounds__(256) k_bn_y1(const float* __restrict__ uu,
                                               const float* __restrict__ bnp,
                                               const float* __restrict__ W1,
                                               float* __restrict__ plane,
                                               u16* __restrict__ y1) {
    __shared__ float W1s[CD][CD];
    __shared__ float bnsp[NK][68];  // padded: [k][j*2+s]
    int tid = threadIdx.x;
    for (int i = tid; i < CD * CD; i += 256) W1s[i >> 5][i & 31] = W1[i];
    bnsp[tid >> 6][tid & 63] = bnp[tid & 255];
    __syncthreads();

    int gid = blockIdx.x * 256 + tid;
    int node = gid >> 5;
    int sub = gid & 31;
    int k = sub >> 3;
    int j4 = (sub & 7) * 4;

    const float* ur = uu + (size_t)node * FD + k * CD;
    float acc0 = 0.f, acc1 = 0.f, acc2 = 0.f, acc3 = 0.f;
#pragma unroll
    for (int q = 0; q < 8; ++q) {
        float4 uv = *(const float4*)(ur + q * 4);
        float4 p0 = *(const float4*)&bnsp[k][q * 8];
        float4 p1 = *(const float4*)&bnsp[k][q * 8 + 4];
        float h0 = fmaxf(fmaf(uv.x, p0.x, p0.y), 0.f);
        float h1 = fmaxf(fmaf(uv.y, p0.z, p0.w), 0.f);
        float h2 = fmaxf(fmaf(uv.z, p1.x, p1.y), 0.f);
        float h3 = fmaxf(fmaf(uv.w, p1.z, p1.w), 0.f);
        float4 w0 = *(const float4*)&W1s[q * 4 + 0][j4];
        float4 w1 = *(const float4*)&W1s[q * 4 + 1][j4];
        float4 w2 = *(const float4*)&W1s[q * 4 + 2][j4];
        float4 w3 = *(const float4*)&W1s[q * 4 + 3][j4];
        acc0 += h0 * w0.x + h1 * w1.x + h2 * w2.x + h3 * w3.x;
        acc1 += h0 * w0.y + h1 * w1.y + h2 * w2.y + h3 * w3.y;
        acc2 += h0 * w0.z + h1 * w1.z + h2 * w2.z + h3 * w3.z;
        acc3 += h0 * w0.w + h1 * w1.w + h2 * w2.w + h3 * w3.w;
    }
    float4 uo = *(const float4*)(uu + (size_t)node * FD + sub * 4);
    float4 q0 = *(const float4*)&bnsp[k][(sub & 7) * 8];
    float4 q1 = *(const float4*)&bnsp[k][(sub & 7) * 8 + 4];
    float4 po;
    po.x = fmaxf(fmaf(uo.x, q0.x, q0.y), 0.f);
    po.y = fmaxf(fmaf(uo.y, q0.z, q0.w), 0.f);
    po.z = fmaxf(fmaf(uo.z, q1.x, q1.y), 0.f);
    po.w = fmaxf(fmaf(uo.w, q1.z, q1.w), 0.f);
    *(float4*)(plane + (size_t)node * FD + sub * 4) = po;   // coalesced

    uint2 pk;
    pk.x = (unsigned)f2bf(acc0) | ((unsigned)f2bf(acc1) << 16);
    pk.y = (unsigned)f2bf(acc2) | ((unsigned)f2bf(acc3) << 16);
    *(uint2*)(y1 + (size_t)node * FD + sub * 4) = pk;       // coalesced
}

// ---------------- final BN apply (layer 1 -> plane2; u [N][128]) ----------------

__global__ void __launch_bounds__(256) k_bn_apply(const float* __restrict__ u,
                                                  const float* __restrict__ bnp,
                                                  float* __restrict__ out) {
    int gid = blockIdx.x * 256 + threadIdx.x;  // over NN*32
    int c0 = (gid & 31) * 4;
    float4 v = *(const float4*)(u + (size_t)gid * 4);
    float4 s0 = *(const float4*)(bnp + c0 * 2);
    float4 s1 = *(const float4*)(bnp + c0 * 2 + 4);
    float4 o;
    o.x = fmaxf(fmaf(v.x, s0.x, s0.y), 0.f);
    o.y = fmaxf(fmaf(v.y, s0.z, s0.w), 0.f);
    o.z = fmaxf(fmaf(v.z, s1.x, s1.y), 0.f);
    o.w = fmaxf(fmaf(v.w, s1.z, s1.w), 0.f);
    *(float4*)(out + (size_t)gid * 4) = o;
}

// ---------------- launch ----------------

extern "C" void kernel_launch(void* const* d_in, const int* in_sizes, int n_in,
                              void* d_out, int out_size, void* d_ws, size_t ws_size,
                              hipStream_t stream) {
    const float* x = (const float*)d_in[0];
    const int* ei = (const int*)d_in[1];
    const float* ew = (const float*)d_in[2];
    const float* l0W1 = (const float*)d_in[3];
    const float* l0b1 = (const float*)d_in[4];
    const float* l0W2 = (const float*)d_in[5];
    const float* l0b2 = (const float*)d_in[6];
    const float* l0g = (const float*)d_in[7];
    const float* l0be = (const float*)d_in[8];
    const float* l1W1 = (const float*)d_in[9];
    const float* l1b1 = (const float*)d_in[10];
    const float* l1W2 = (const float*)d_in[11];
    const float* l1b2 = (const float*)d_in[12];
    const float* l1g = (const float*)d_in[13];
    const float* l1be = (const float*)d_in[14];
    const float* encW = (const float*)d_in[15];
    const float* encb = (const float*)d_in[16];
    float* out = (float*)d_out;

    char* ws = (char*)d_ws;
    size_t off = 0;
    auto alloc = [&](size_t bytes) -> void* {
        void* p = ws + off;
        off += (bytes + 255) & ~(size_t)255;
        return p;
    };
    int* dcnt = (int*)alloc((size_t)NN * 4);
    int4* dsse = (int4*)alloc((size_t)NN * CAP * 16);       // 38.4MB fixed-cap CSR
    u16* dy0 = (u16*)alloc((size_t)NN * CD * 2);            // bf16 y0 (3.2MB)
    u16* dy1 = (u16*)alloc((size_t)NN * FD * 2);            // bf16 y1 (12.8MB)
    float* du = (float*)alloc((size_t)NN * FD * 4);         // u fp32 [N][128] (25.6MB)
    float* dpart = (float*)alloc((size_t)BNCH * FD * 2 * 4);  // 1MB
    float* dbnp = (float*)alloc((size_t)FD * 2 * 4);

    const int* src = ei;
    const int* dst = ei + NE;

    // XCD-binned fixed-cap CSR scatter (runs alone: co-residency hurts, r11/r14)
    hipMemsetAsync(dcnt, 0, (size_t)NN * 4, stream);
    k_scatter<<<(NE / 256) * 8, 256, 0, stream>>>(src, dst, ew, dcnt, dsse);
    k_enc_y0<<<(NN + 63) / 64, 256, 0, stream>>>(x, encW, encb, l0W1, out, dy0);

    // ---- layer 0 -> plane 1 ----
    float* plane1 = out + (size_t)NN * FD;
    k_aggr<CD><<<NN / 16, 256, 0, stream>>>(dy0, dcnt, dsse, l0b1, l0W2, l0b2, du);
    k_bn_stats1<<<BNCH, 256, 0, stream>>>(du, dpart);
    k_bn_stats2<<<FD, 256, 0, stream>>>(dpart, l0g, l0be, dbnp);
    k_bn_y1<<<NN * 32 / 256, 256, 0, stream>>>(du, dbnp, l1W1, plane1, dy1);

    // ---- layer 1 -> plane 2 ----
    float* plane2 = out + (size_t)2 * NN * FD;
    k_aggr<FD><<<NN / 16, 256, 0, stream>>>(dy1, dcnt, dsse, l1b1, l1W2, l1b2, du);
    k_bn_stats1<<<BNCH, 256, 0, stream>>>(du, dpart);
    k_bn_stats2<<<FD, 256, 0, stream>>>(dpart, l1g, l1be, dbnp);
    k_bn_apply<<<NN * 32 / 256, 256, 0, stream>>>(du, dbnp, plane2);
}

// Round 22
// 225.040 us; speedup vs baseline: 1.0188x; 1.0188x over previous
//
#include <hip/hip_runtime.h>
#include <hip/hip_bf16.h>
#include <math.h>

#define NN 50000
#define NE 800000
#define NK 4
#define FD 128
#define CD 32
#define CAP 48       // fixed per-node CSR capacity
#define BNCH 1000    // bn stat chunks (50 rows each)
#define BNROWS 50
#define NRANGE 6250  // NN/8 nodes per XCD range

typedef unsigned short u16;

__device__ __forceinline__ u16 f2bf(float x) {
    union { float f; unsigned u; } c; c.f = x;
    unsigned r = c.u + 0x7fffu + ((c.u >> 16) & 1u);  // RNE
    return (u16)(r >> 16);
}
__device__ __forceinline__ float bflo(unsigned pair) {
    union { unsigned u; float f; } c; c.u = pair << 16;
    return c.f;
}
__device__ __forceinline__ float bfhi(unsigned pair) {
    union { unsigned u; float f; } c; c.u = pair & 0xffff0000u;
    return c.f;
}

// ---------------- XCD-binned fixed-cap CSR scatter ----------------

__global__ void k_scatter(const int* __restrict__ src, const int* __restrict__ dst,
                          const float* __restrict__ ew,
                          int* __restrict__ cnt, int4* __restrict__ sse) {
    int xcd = blockIdx.x & 7;
    int e = (blockIdx.x >> 3) * 256 + threadIdx.x;   // NE divisible by 256
    int d = dst[e];
    int lo = xcd * NRANGE;
    if ((unsigned)(d - lo) < (unsigned)NRANGE) {
        int p = atomicAdd(&cnt[d], 1);
        unsigned w01 = (unsigned)f2bf(ew[e]) | ((unsigned)f2bf(ew[(size_t)NE + e]) << 16);
        unsigned w23 = (unsigned)f2bf(ew[(size_t)2 * NE + e]) | ((unsigned)f2bf(ew[(size_t)3 * NE + e]) << 16);
        sse[(size_t)d * CAP + p] = make_int4(src[e], (int)w01, (int)w23, 0);
    }
}

// ---------------- fused encoder + y0 (y0 stored bf16 [N][32]) ----------------

__global__ void __launch_bounds__(256) k_enc_y0(const float* __restrict__ x,
                                                const float* __restrict__ W,
                                                const float* __restrict__ b,
                                                const float* __restrict__ W1,
                                                float* __restrict__ out,
                                                u16* __restrict__ y0) {
    __shared__ float xsT[FD][68];
    int tid = threadIdx.x;
    int nbase = blockIdx.x * 64;

    int r = tid >> 2;
    int cg = (tid & 3) * 32;
    int gn = nbase + r;
    const float* xr = x + (size_t)(gn < NN ? gn : NN - 1) * FD;
#pragma unroll
    for (int q = 0; q < 8; ++q) {
        float4 v = *(const float4*)(xr + cg + q * 4);
        int f = cg + q * 4;
        xsT[f][r] = v.x; xsT[f + 1][r] = v.y; xsT[f + 2][r] = v.z; xsT[f + 3][r] = v.w;
    }
    __syncthreads();

    int cq = (tid & 31) * 4;
    int col = tid & 31;
    int g = tid >> 5;
    float acc[8][4];
    float acy[8];
#pragma unroll
    for (int i = 0; i < 8; ++i) {
        acy[i] = 0.f;
#pragma unroll
        for (int j = 0; j < 4; ++j) acc[i][j] = 0.f;
    }

    for (int f = 0; f < FD; ++f) {
        float4 wv = *(const float4*)(W + f * FD + cq);
        float w1 = W1[f * CD + col];
        float4 xa = *(const float4*)&xsT[f][g * 8];
        float4 xb = *(const float4*)&xsT[f][g * 8 + 4];
        float xn[8] = {xa.x, xa.y, xa.z, xa.w, xb.x, xb.y, xb.z, xb.w};
#pragma unroll
        for (int i = 0; i < 8; ++i) {
            acc[i][0] += xn[i] * wv.x;
            acc[i][1] += xn[i] * wv.y;
            acc[i][2] += xn[i] * wv.z;
            acc[i][3] += xn[i] * wv.w;
            acy[i] += xn[i] * w1;
        }
    }
    float4 bv = *(const float4*)(b + cq);
#pragma unroll
    for (int i = 0; i < 8; ++i) {
        int n = nbase + g * 8 + i;
        if (n < NN) {
            float4 o;
            o.x = acc[i][0] + bv.x;
            o.y = acc[i][1] + bv.y;
            o.z = acc[i][2] + bv.z;
            o.w = acc[i][3] + bv.w;
            *(float4*)(out + (size_t)n * FD + cq) = o;
            y0[(size_t)n * CD + col] = f2bf(acy[i]);
        }
    }
}

// ---------------- fused aggregation + relu + MLP2 -> u fp32 [N][128] ----------------
// Block = 16 nodes: 4 waves x 4 serial nodes each. Per node: HALF-WAVE per edge;
// t parked in padded LDS; same wave does t@W2+b2. (round-17/20 configuration: best)

template <int STRIDE>
__global__ void __launch_bounds__(256) k_aggr(const u16* __restrict__ y,
                                              const int* __restrict__ cnt,
                                              const int4* __restrict__ sse,
                                              const float* __restrict__ b1,
                                              const float* __restrict__ W2,
                                              const float* __restrict__ b2,
                                              float* __restrict__ u) {
    __shared__ float W2s[CD][CD];
    __shared__ float b2s[CD];
    __shared__ float tls[4][NK][36];   // per-wave slot; stride 36 dwords conflict-free
    int tid = threadIdx.x;
    for (int i = tid; i < CD * CD; i += 256) W2s[i >> 5][i & 31] = W2[i];
    if (tid < CD) b2s[tid] = b2[tid];
    __syncthreads();

    int w = tid >> 6;
    int lane = tid & 63;
    int hi = lane >> 5;
    int sub = lane & 31;
    int k = sub >> 3;
    int fq = sub & 7;
    int f0 = fq * 4;
    int col = (STRIDE == CD) ? f0 : (k * CD + f0);
    const u16* yb = y + col;
    bool klow = k < 2;
    int lsh = (k & 1) ? 0 : 16;

    int nbase0 = blockIdx.x * 16 + w * 4;
    int4 c4 = *(const int4*)(cnt + nbase0);          // 4 node degrees in one load
    int cdeg[4] = {c4.x, c4.y, c4.z, c4.w};

    float4 bv = *(const float4*)(b1 + f0);
    float4 b2v = *(const float4*)&b2s[f0];

#pragma unroll 1
    for (int it = 0; it < 4; ++it) {
        int node = nbase0 + it;
        int beg = node * CAP;
        int end = beg + cdeg[it];

        float a0 = 0.f, a1 = 0.f, a2 = 0.f, a3 = 0.f;
        for (int j0 = beg; j0 < end; j0 += 8) {
            int ssv[4];
            float wwv[4];
#pragma unroll
            for (int q = 0; q < 4; ++q) {
                int jj = j0 + q * 2 + hi;
                bool ok = jj < end;
                int jc = ok ? jj : beg;
                int4 ee = sse[jc];
                ssv[q] = ee.x;
                unsigned wp = klow ? (unsigned)ee.y : (unsigned)ee.z;
                unsigned wb = (wp << lsh) & 0xffff0000u;
                union { unsigned u; float f; } cv; cv.u = wb;
                wwv[q] = ok ? cv.f : 0.f;
            }
#pragma unroll
            for (int q = 0; q < 4; ++q) {
                uint2 pv = *(const uint2*)(yb + (size_t)ssv[q] * STRIDE);
                float wq = wwv[q];
                a0 += wq * bflo(pv.x);
                a1 += wq * bfhi(pv.x);
                a2 += wq * bflo(pv.y);
                a3 += wq * bfhi(pv.y);
            }
        }
        a0 += __shfl_xor(a0, 32);
        a1 += __shfl_xor(a1, 32);
        a2 += __shfl_xor(a2, 32);
        a3 += __shfl_xor(a3, 32);

        uint2 hv = *(const uint2*)(yb + (size_t)node * STRIDE);
        float t0 = fmaxf(bflo(hv.x) + a0 + bv.x, 0.f);
        float t1 = fmaxf(bfhi(hv.x) + a1 + bv.y, 0.f);
        float t2 = fmaxf(bflo(hv.y) + a2 + bv.z, 0.f);
        float t3 = fmaxf(bfhi(hv.y) + a3 + bv.w, 0.f);
        if (hi == 0) {
            float4 tv = {t0, t1, t2, t3};
            *(float4*)&tls[w][k][f0] = tv;
        }
        __threadfence_block();  // wave-local LDS ordering

        // MLP2: u[node][k*32+f0..+3] = sum_m t[m]*W2[m][f0..+3] + b2
        int m0 = hi * 16;
        float c0 = 0.f, c1 = 0.f, c2 = 0.f, c3 = 0.f;
#pragma unroll
        for (int mm = 0; mm < 16; ++mm) {
            float tm = tls[w][k][m0 + mm];
            float4 wv = *(const float4*)&W2s[m0 + mm][f0];
            c0 += tm * wv.x;
            c1 += tm * wv.y;
            c2 += tm * wv.z;
            c3 += tm * wv.w;
        }
        c0 += __shfl_xor(c0, 32);
        c1 += __shfl_xor(c1, 32);
        c2 += __shfl_xor(c2, 32);
        c3 += __shfl_xor(c3, 32);
        if (hi == 0) {
            float4 o = {c0 + b2v.x, c1 + b2v.y, c2 + b2v.z, c3 + b2v.w};
            *(float4*)(u + (size_t)node * FD + k * CD + f0) = o;   // coalesced
        }
        __threadfence_block();  // tls write of next iter ordered after reads
    }
}

// ---------------- batchnorm stats (two-stage, deterministic; u [N][128]) ----------------

__global__ void __launch_bounds__(256) k_bn_stats1(const float* __restrict__ u,
                                                   float* __restrict__ part) {
    int ch = blockIdx.x;
    int c = threadIdx.x & 127;
    int rg = threadIdx.x >> 7;  // 0/1
    float s1 = 0.f, s2 = 0.f;
    int nend = (ch + 1) * BNROWS;
    for (int n = ch * BNROWS + rg; n < nend; n += 2) {
        float v = u[(size_t)n * FD + c];
        s1 += v;
        s2 += v * v;
    }
    __shared__ float sh1[2][FD], sh2[2][FD];
    sh1[rg][c] = s1;
    sh2[rg][c] = s2;
    __syncthreads();
    if (rg == 0) {
        s1 += sh1[1][c];
        s2 += sh2[1][c];
        float2 p = {s1, s2};
        *(float2*)(part + ((size_t)ch * FD + c) * 2) = p;
    }
}

// stage 2: one block PER FEATURE (128 blocks); 256 threads tree-reduce 1000 chunks.
__global__ void __launch_bounds__(256) k_bn_stats2(const float* __restrict__ part,
                                                   const float* __restrict__ gamma,
                                                   const float* __restrict__ beta,
                                                   float* __restrict__ bnp) {
    int c = blockIdx.x;     // feature 0..127
    int tid = threadIdx.x;
    float S1 = 0.f, S2 = 0.f;
    for (int ch = tid; ch < BNCH; ch += 256) {
        float2 p = *(const float2*)(part + ((size_t)ch * FD + c) * 2);
        S1 += p.x;
        S2 += p.y;
    }
    __shared__ float sh1[256], sh2[256];
    sh1[tid] = S1;
    sh2[tid] = S2;
    __syncthreads();
    for (int off = 128; off > 0; off >>= 1) {
        if (tid < off) {
            sh1[tid] += sh1[tid + off];
            sh2[tid] += sh2[tid + off];
        }
        __syncthreads();
    }
    if (tid == 0) {
        float mean = sh1[0] / (float)NN;
        float var = sh2[0] / (float)NN - mean * mean;
        int f = c & 31;
        float scale = gamma[f] * rsqrtf(var + 1e-5f);
        bnp[c * 2] = scale;
        bnp[c * 2 + 1] = beta[f] - mean * scale;
    }
}

// ---------------- fused BN-apply + y1 (streaming, u [N][128]) ----------------

__global__ void __launch_bounds__(256) k_bn_y1(const float* __restrict__ uu,
                                               const float* __restrict__ bnp,
                                               const float* __restrict__ W1,
                                               float* __restrict__ plane,
                                               u16* __restrict__ y1) {
    __shared__ float W1s[CD][CD];
    __shared__ float bnsp[NK][68];  // padded: [k][j*2+s]
    int tid = threadIdx.x;
    for (int i = tid; i < CD * CD; i += 256) W1s[i >> 5][i & 31] = W1[i];
    bnsp[tid >> 6][tid & 63] = bnp[tid & 255];
    __syncthreads();

    int gid = blockIdx.x * 256 + tid;
    int node = gid >> 5;
    int sub = gid & 31;
    int k = sub >> 3;
    int j4 = (sub & 7) * 4;

    const float* ur = uu + (size_t)node * FD + k * CD;
    float acc0 = 0.f, acc1 = 0.f, acc2 = 0.f, acc3 = 0.f;
#pragma unroll
    for (int q = 0; q < 8; ++q) {
        float4 uv = *(const float4*)(ur + q * 4);
        float4 p0 = *(const float4*)&bnsp[k][q * 8];
        float4 p1 = *(const float4*)&bnsp[k][q * 8 + 4];
        float h0 = fmaxf(fmaf(uv.x, p0.x, p0.y), 0.f);
        float h1 = fmaxf(fmaf(uv.y, p0.z, p0.w), 0.f);
        float h2 = fmaxf(fmaf(uv.z, p1.x, p1.y), 0.f);
        float h3 = fmaxf(fmaf(uv.w, p1.z, p1.w), 0.f);
        float4 w0 = *(const float4*)&W1s[q * 4 + 0][j4];
        float4 w1 = *(const float4*)&W1s[q * 4 + 1][j4];
        float4 w2 = *(const float4*)&W1s[q * 4 + 2][j4];
        float4 w3 = *(const float4*)&W1s[q * 4 + 3][j4];
        acc0 += h0 * w0.x + h1 * w1.x + h2 * w2.x + h3 * w3.x;
        acc1 += h0 * w0.y + h1 * w1.y + h2 * w2.y + h3 * w3.y;
        acc2 += h0 * w0.z + h1 * w1.z + h2 * w2.z + h3 * w3.z;
        acc3 += h0 * w0.w + h1 * w1.w + h2 * w2.w + h3 * w3.w;
    }
    float4 uo = *(const float4*)(uu + (size_t)node * FD + sub * 4);
    float4 q0 = *(const float4*)&bnsp[k][(sub & 7) * 8];
    float4 q1 = *(const float4*)&bnsp[k][(sub & 7) * 8 + 4];
    float4 po;
    po.x = fmaxf(fmaf(uo.x, q0.x, q0.y), 0.f);
    po.y = fmaxf(fmaf(uo.y, q0.z, q0.w), 0.f);
    po.z = fmaxf(fmaf(uo.z, q1.x, q1.y), 0.f);
    po.w = fmaxf(fmaf(uo.w, q1.z, q1.w), 0.f);
    *(float4*)(plane + (size_t)node * FD + sub * 4) = po;   // coalesced

    uint2 pk;
    pk.x = (unsigned)f2bf(acc0) | ((unsigned)f2bf(acc1) << 16);
    pk.y = (unsigned)f2bf(acc2) | ((unsigned)f2bf(acc3) << 16);
    *(uint2*)(y1 + (size_t)node * FD + sub * 4) = pk;       // coalesced
}

// ---------------- final BN apply (layer 1 -> plane2; u [N][128]) ----------------

__global__ void __launch_bounds__(256) k_bn_apply(const float* __restrict__ u,
                                                  const float* __restrict__ bnp,
                                                  float* __restrict__ out) {
    int gid = blockIdx.x * 256 + threadIdx.x;  // over NN*32
    int c0 = (gid & 31) * 4;
    float4 v = *(const float4*)(u + (size_t)gid * 4);
    float4 s0 = *(const float4*)(bnp + c0 * 2);
    float4 s1 = *(const float4*)(bnp + c0 * 2 + 4);
    float4 o;
    o.x = fmaxf(fmaf(v.x, s0.x, s0.y), 0.f);
    o.y = fmaxf(fmaf(v.y, s0.z, s0.w), 0.f);
    o.z = fmaxf(fmaf(v.z, s1.x, s1.y), 0.f);
    o.w = fmaxf(fmaf(v.w, s1.z, s1.w), 0.f);
    *(float4*)(out + (size_t)gid * 4) = o;
}

// ---------------- launch ----------------

extern "C" void kernel_launch(void* const* d_in, const int* in_sizes, int n_in,
                              void* d_out, int out_size, void* d_ws, size_t ws_size,
                              hipStream_t stream) {
    const float* x = (const float*)d_in[0];
    const int* ei = (const int*)d_in[1];
    const float* ew = (const float*)d_in[2];
    const float* l0W1 = (const float*)d_in[3];
    const float* l0b1 = (const float*)d_in[4];
    const float* l0W2 = (const float*)d_in[5];
    const float* l0b2 = (const float*)d_in[6];
    const float* l0g = (const float*)d_in[7];
    const float* l0be = (const float*)d_in[8];
    const float* l1W1 = (const float*)d_in[9];
    const float* l1b1 = (const float*)d_in[10];
    const float* l1W2 = (const float*)d_in[11];
    const float* l1b2 = (const float*)d_in[12];
    const float* l1g = (const float*)d_in[13];
    const float* l1be = (const float*)d_in[14];
    const float* encW = (const float*)d_in[15];
    const float* encb = (const float*)d_in[16];
    float* out = (float*)d_out;

    char* ws = (char*)d_ws;
    size_t off = 0;
    auto alloc = [&](size_t bytes) -> void* {
        void* p = ws + off;
        off += (bytes + 255) & ~(size_t)255;
        return p;
    };
    int* dcnt = (int*)alloc((size_t)NN * 4);
    int4* dsse = (int4*)alloc((size_t)NN * CAP * 16);       // 38.4MB fixed-cap CSR
    u16* dy0 = (u16*)alloc((size_t)NN * CD * 2);            // bf16 y0 (3.2MB)
    u16* dy1 = (u16*)alloc((size_t)NN * FD * 2);            // bf16 y1 (12.8MB)
    float* du = (float*)alloc((size_t)NN * FD * 4);         // u fp32 [N][128] (25.6MB)
    float* dpart = (float*)alloc((size_t)BNCH * FD * 2 * 4);  // 1MB
    float* dbnp = (float*)alloc((size_t)FD * 2 * 4);

    const int* src = ei;
    const int* dst = ei + NE;

    // XCD-binned fixed-cap CSR scatter (runs alone: co-residency hurts, r11/r14)
    hipMemsetAsync(dcnt, 0, (size_t)NN * 4, stream);
    k_scatter<<<(NE / 256) * 8, 256, 0, stream>>>(src, dst, ew, dcnt, dsse);
    k_enc_y0<<<(NN + 63) / 64, 256, 0, stream>>>(x, encW, encb, l0W1, out, dy0);

    // ---- layer 0 -> plane 1 ----
    float* plane1 = out + (size_t)NN * FD;
    k_aggr<CD><<<NN / 16, 256, 0, stream>>>(dy0, dcnt, dsse, l0b1, l0W2, l0b2, du);
    k_bn_stats1<<<BNCH, 256, 0, stream>>>(du, dpart);
    k_bn_stats2<<<FD, 256, 0, stream>>>(dpart, l0g, l0be, dbnp);
    k_bn_y1<<<NN * 32 / 256, 256, 0, stream>>>(du, dbnp, l1W1, plane1, dy1);

    // ---- layer 1 -> plane 2 ----
    float* plane2 = out + (size_t)2 * NN * FD;
    k_aggr<FD><<<NN / 16, 256, 0, stream>>>(dy1, dcnt, dsse, l1b1, l1W2, l1b2, du);
    k_bn_stats1<<<BNCH, 256, 0, stream>>>(du, dpart);
    k_bn_stats2<<<FD, 256, 0, stream>>>(dpart, l1g, l1be, dbnp);
    k_bn_apply<<<NN * 32 / 256, 256, 0, stream>>>(du, dbnp, plane2);
}